// Round 3
// baseline (544.244 us; speedup 1.0000x reference)
//
#include <hip/hip_runtime.h>
#include <hip/hip_bf16.h>

// ---------------------------------------------------------------------------
// Quantum ViT: B=128, T=127, D_IN=48, DK=S=128, H=8, L=6, P=8128
// Inputs: all float32 (per reference). Output: float32 [B, DK].
// Internals: bf16 MFMA (16x16x32) for the 4 matmuls per (layer,head);
// f32 residual path; comparison is done by the harness in bf16 space (2%).
//
// Pipeline:
//   0) vw_bf16 : Vw f32 -> bf16 canon (B-operand staging)
//   1) build_w : 48 orthogonal 128x128 Givens-pyramid matrices -> Wt=W^T bf16
//   2) embed   : x@Ew^T + class token, LN0 -> h_f32, h_bf16, inv_n
//   3) per layer: attn (per (head,batch) WG, fused 4-matmul attention)
//                 merge (sum heads + next-layer prep; last writes d_out f32)
// ---------------------------------------------------------------------------

typedef __bf16 bf16x8 __attribute__((ext_vector_type(8)));
typedef float  f32x4  __attribute__((ext_vector_type(4)));
typedef unsigned int u32;

#define LDH 136  // padded LDS row stride in bf16 elems

// ---------------------------------------------------------------------------
// 0) Vw f32 -> bf16
// ---------------------------------------------------------------------------
__global__ void __launch_bounds__(256)
vw_bf16_kernel(const float* __restrict__ vw, __bf16* __restrict__ cvw)
{
    int i = (blockIdx.x * 256 + threadIdx.x) * 4;   // 786432 elems / 4
#pragma unroll
    for (int j = 0; j < 4; j++) cvw[i + j] = (__bf16)vw[i + j];
}

// ---------------------------------------------------------------------------
// 1) W build: pyramid of 8128 Givens rotations, re-scheduled into 253
//    parallel layers via time(k,i)=2k-i (program order preserved for every
//    wire-sharing pair; within a layer pairs are disjoint, same parity).
//    Lane lam holds components (2lam, 2lam+1) of 8 columns in registers.
//    Even layer: in-lane rotate; odd layer: one shfl each way.
//    Output: Wt[mat][c][d] = W[d][c]  (B-operand layout for T1 = h @ W).
// ---------------------------------------------------------------------------
__global__ void __launch_bounds__(64)
build_w_kernel(const float* __restrict__ phi, __bf16* __restrict__ wt)
{
    const int mat = blockIdx.x >> 4;
    const int grp = blockIdx.x & 15;
    const int c0  = grp * 8;
    const int lam = threadIdx.x;

    const float* ph = phi + mat * 8128;

    float vlo[8], vhi[8];
#pragma unroll
    for (int j = 0; j < 8; j++) {
        vlo[j] = (2 * lam     == c0 + j) ? 1.f : 0.f;
        vhi[j] = (2 * lam + 1 == c0 + j) ? 1.f : 0.f;
    }

    for (int t = 0; t < 253; t++) {
        const int p   = t & 1;
        const int i   = 2 * lam + p;
        const int lim = min(t, 252 - t);
        const bool act = (i <= lim);
        const int k   = (t + i) >> 1;
        const int idx = act ? ((k * (k + 1)) >> 1) + (k - i) : 0;
        const float th = act ? ph[idx] : 0.f;    // theta=0 -> identity
        float sn, cs;
        __sincosf(th, &sn, &cs);

        if (p == 0) {
#pragma unroll
            for (int j = 0; j < 8; j++) {
                float lo = vlo[j], hi = vhi[j];
                vlo[j] = cs * lo - sn * hi;
                vhi[j] = sn * lo + cs * hi;
            }
        } else {
#pragma unroll
            for (int j = 0; j < 8; j++) {
                float y  = __shfl_down(vlo[j], 1);   // W[2lam+2][c] from lane lam+1
                float x  = vhi[j];                   // W[2lam+1][c]
                float xn = cs * x - sn * y;
                float yn = sn * x + cs * y;
                vhi[j] = xn;
                float z = __shfl_up(yn, 1);          // new W[2lam][c] from lane lam-1
                if (lam > 0) vlo[j] = z;
            }
        }
    }

    u32* wtu = (u32*)wt;
#pragma unroll
    for (int j = 0; j < 8; j++) {
        __bf16 a = (__bf16)vlo[j];
        __bf16 b = (__bf16)vhi[j];
        u32 pk = (u32)__builtin_bit_cast(unsigned short, a)
               | ((u32)__builtin_bit_cast(unsigned short, b) << 16);
        wtu[mat * 8192 + (c0 + j) * 64 + lam] = pk;   // Wt[mat][c0+j][2lam..2lam+1]
    }
}

// ---------------------------------------------------------------------------
static __device__ __forceinline__ float block_sum_128(float v, float* sred)
{
#pragma unroll
    for (int m = 32; m; m >>= 1) v += __shfl_xor(v, m);
    __syncthreads();
    if ((threadIdx.x & 63) == 0) sred[threadIdx.x >> 6] = v;
    __syncthreads();
    return sred[0] + sred[1];
}

// ---------------------------------------------------------------------------
// 2) embed: tok = x @ Ew^T + eb (class token at s=0), LN0 -> h_f32/h_bf16/inv_n
//    grid = s*128 + b, 128 threads (d)
// ---------------------------------------------------------------------------
__global__ void __launch_bounds__(128)
embed_kernel(const float* __restrict__ x,  const float* __restrict__ ew,
             const float* __restrict__ eb, const float* __restrict__ ct,
             const float* __restrict__ g0, const float* __restrict__ b0,
             float* __restrict__ hf, __bf16* __restrict__ hb, float* __restrict__ invn)
{
    __shared__ float sx[48];
    __shared__ float sred[2];
    const int b = blockIdx.x & 127, s = blockIdx.x >> 7, d = threadIdx.x;

    float val;
    if (s == 0) {
        val = ct[d];
    } else {
        if (d < 48) sx[d] = x[(b * 127 + (s - 1)) * 48 + d];
        __syncthreads();
        float a = 0.f;
#pragma unroll
        for (int f = 0; f < 48; f++) a = fmaf(sx[f], ew[d * 48 + f], a);
        val = a + eb[d];
    }
    float mean = block_sum_128(val, sred) * (1.f / 128.f);
    float xc   = val - mean;
    float var  = block_sum_128(xc * xc, sred) * (1.f / 128.f);
    float y    = xc * rsqrtf(var + 1e-5f) * g0[d] + b0[d];
    float ss   = block_sum_128(y * y, sred);

    const int o = (b * 128 + s) * 128 + d;
    hf[o] = y;
    hb[o] = (__bf16)y;
    if (d == 0) invn[b * 128 + s] = rsqrtf(ss);
}

// ---------------------------------------------------------------------------
// 3) fused attention head: one WG per (head, batch). 512 thr = 8 waves,
//    wave w owns rows 16w..16w+15 of every 128x128 matmul.
//    A: T1 = h @ W -> sT   | B: G = T1 @ h^T, softmax -> Pm in sT
//    C: V = h @ Vw^T       | D: O = Pm @ V, +h, LN, *mw -> hs
//    scores = G^2 * inv_ns * inv_nt * scale   (== M^2 * n_s n_t * scale)
// ---------------------------------------------------------------------------
__global__ void __launch_bounds__(512, 2)
attn_kernel(int l,
            const float*  __restrict__ hf,  const __bf16* __restrict__ hb,
            const float*  __restrict__ invn, const __bf16* __restrict__ wt,
            const __bf16* __restrict__ vw,  const float* __restrict__ vb,
            const float* __restrict__ lng,  const float* __restrict__ lnb,
            const float* __restrict__ mwp,  __bf16* __restrict__ hs)
{
    __shared__ __align__(16) __bf16 sH[128 * LDH];
    __shared__ __align__(16) __bf16 sB[128 * LDH];
    __shared__ __align__(16) __bf16 sT[128 * LDH];
    __shared__ float sInv[128];
    __shared__ float sVb[128];
    __shared__ float sLg[128];
    __shared__ float sLb[128];

    const int tid  = threadIdx.x;
    const int lane = tid & 63, wave = tid >> 6;
    const int l15  = lane & 15, quad = lane >> 4;
    const int b    = blockIdx.x & 127;
    const int hh   = blockIdx.x >> 7;
    const int lh   = l * 8 + hh;

    const __bf16* hbp = hb + b * 16384;
    const __bf16* wtp = wt + lh * 16384;
    const __bf16* vwp = vw + lh * 16384;

    bf16x8 vwr[4];
#pragma unroll
    for (int c = 0; c < 4; c++) {
        int ch  = tid + c * 512;
        int row = ch >> 4, cc = ch & 15;
        bf16x8 hv = *(const bf16x8*)(hbp + ch * 8);
        bf16x8 wv = *(const bf16x8*)(wtp + ch * 8);
        vwr[c]    = *(const bf16x8*)(vwp + ch * 8);
        *(bf16x8*)(&sH[row * LDH + cc * 8]) = hv;
        *(bf16x8*)(&sB[row * LDH + cc * 8]) = wv;
    }
    if (tid < 128) {
        sInv[tid] = invn[b * 128 + tid];
        sVb[tid]  = vb[lh * 128 + tid];
        sLg[tid]  = lng[lh * 128 + tid];
        sLb[tid]  = lnb[lh * 128 + tid];
    }
    __syncthreads();  // B1

    const int rowA = wave * 16 + l15;       // A-frag: m = lane&15
    const int kq   = quad * 8;              // A/B-frag: k = quad*8 + j
    const int srow = wave * 16 + quad * 4;  // C/D: row = quad*4 + reg
    const f32x4 vzero = {0.f, 0.f, 0.f, 0.f};

    f32x4 acc[8];

    // ================= Phase A: T1 = h @ W =================
#pragma unroll
    for (int t = 0; t < 8; t++) acc[t] = vzero;
#pragma unroll
    for (int k0 = 0; k0 < 128; k0 += 32) {
        bf16x8 af = *(const bf16x8*)(&sH[rowA * LDH + k0 + kq]);
#pragma unroll
        for (int t = 0; t < 8; t++) {
            bf16x8 bf = *(const bf16x8*)(&sB[(t * 16 + l15) * LDH + k0 + kq]);
            acc[t] = __builtin_amdgcn_mfma_f32_16x16x32_bf16(af, bf, acc[t], 0, 0, 0);
        }
    }
#pragma unroll
    for (int t = 0; t < 8; t++)
#pragma unroll
        for (int r = 0; r < 4; r++)
            sT[(srow + r) * LDH + t * 16 + l15] = (__bf16)acc[t][r];

    __syncthreads();  // B2: all done reading sB(Wt)

#pragma unroll
    for (int c = 0; c < 4; c++) {
        int ch = tid + c * 512; int row = ch >> 4, cc = ch & 15;
        *(bf16x8*)(&sB[row * LDH + cc * 8]) = vwr[c];
    }

    // ================= Phase B: G = T1 @ h^T =================
#pragma unroll
    for (int t = 0; t < 8; t++) acc[t] = vzero;
#pragma unroll
    for (int k0 = 0; k0 < 128; k0 += 32) {
        bf16x8 af = *(const bf16x8*)(&sT[rowA * LDH + k0 + kq]);
#pragma unroll
        for (int t = 0; t < 8; t++) {
            bf16x8 bf = *(const bf16x8*)(&sH[(t * 16 + l15) * LDH + k0 + kq]);
            acc[t] = __builtin_amdgcn_mfma_f32_16x16x32_bf16(af, bf, acc[t], 0, 0, 0);
        }
    }

    // ---- softmax over cols:  A = G^2 * inv_ns * inv_nt * scale ----
    {
        const float scale = 0.08838834764831843f;  // 1/sqrt(128)
        float invs[4], invt[8];
#pragma unroll
        for (int r = 0; r < 4; r++) invs[r] = sInv[srow + r];
#pragma unroll
        for (int t = 0; t < 8; t++) invt[t] = sInv[t * 16 + l15];

        float mx[4] = {-3e38f, -3e38f, -3e38f, -3e38f};
#pragma unroll
        for (int t = 0; t < 8; t++)
#pragma unroll
            for (int r = 0; r < 4; r++) {
                float g = acc[t][r];
                float v = g * g * invs[r] * invt[t] * scale;
                acc[t][r] = v;
                mx[r] = fmaxf(mx[r], v);
            }
#pragma unroll
        for (int m = 1; m < 16; m <<= 1)
#pragma unroll
            for (int r = 0; r < 4; r++) mx[r] = fmaxf(mx[r], __shfl_xor(mx[r], m));

        float sm[4] = {0.f, 0.f, 0.f, 0.f};
#pragma unroll
        for (int t = 0; t < 8; t++)
#pragma unroll
            for (int r = 0; r < 4; r++) {
                float e = __expf(acc[t][r] - mx[r]);
                acc[t][r] = e;
                sm[r] += e;
            }
#pragma unroll
        for (int m = 1; m < 16; m <<= 1)
#pragma unroll
            for (int r = 0; r < 4; r++) sm[r] += __shfl_xor(sm[r], m);
#pragma unroll
        for (int r = 0; r < 4; r++) sm[r] = 1.0f / sm[r];
#pragma unroll
        for (int t = 0; t < 8; t++)
#pragma unroll
            for (int r = 0; r < 4; r++)
                sT[(srow + r) * LDH + t * 16 + l15] = (__bf16)(acc[t][r] * sm[r]);
    }

    float hres[8][4];
    {
        const float* hfp = hf + (b * 128 + srow) * 128;
#pragma unroll
        for (int t = 0; t < 8; t++)
#pragma unroll
            for (int r = 0; r < 4; r++)
                hres[t][r] = hfp[r * 128 + t * 16 + l15];
    }

    __syncthreads();  // B3: Vw->sB visible

    // ================= Phase C: V = h @ Vw^T =================
#pragma unroll
    for (int t = 0; t < 8; t++) acc[t] = vzero;
#pragma unroll
    for (int k0 = 0; k0 < 128; k0 += 32) {
        bf16x8 af = *(const bf16x8*)(&sH[rowA * LDH + k0 + kq]);
#pragma unroll
        for (int t = 0; t < 8; t++) {
            bf16x8 bf = *(const bf16x8*)(&sB[(t * 16 + l15) * LDH + k0 + kq]);
            acc[t] = __builtin_amdgcn_mfma_f32_16x16x32_bf16(af, bf, acc[t], 0, 0, 0);
        }
    }
    __syncthreads();  // B4: all done reading sH

    {   // V^T into sH: sH[e][token]
        float vbv[8];
#pragma unroll
        for (int t = 0; t < 8; t++) vbv[t] = sVb[t * 16 + l15];
#pragma unroll
        for (int t = 0; t < 8; t++)
#pragma unroll
            for (int r = 0; r < 4; r++)
                sH[(t * 16 + l15) * LDH + srow + r] = (__bf16)(acc[t][r] + vbv[t]);
    }
    __syncthreads();  // B5

    // ================= Phase D: O = Pm @ V =================
#pragma unroll
    for (int t = 0; t < 8; t++) acc[t] = vzero;
#pragma unroll
    for (int k0 = 0; k0 < 128; k0 += 32) {
        bf16x8 af = *(const bf16x8*)(&sT[rowA * LDH + k0 + kq]);
#pragma unroll
        for (int t = 0; t < 8; t++) {
            bf16x8 bf = *(const bf16x8*)(&sH[(t * 16 + l15) * LDH + k0 + kq]);
            acc[t] = __builtin_amdgcn_mfma_f32_16x16x32_bf16(af, bf, acc[t], 0, 0, 0);
        }
    }

    {   // epilogue: +h, LN over d, *merger_w -> hs
        const float mw = mwp[lh];
        float sum_[4] = {0.f, 0.f, 0.f, 0.f};
        float sq_[4]  = {0.f, 0.f, 0.f, 0.f};
#pragma unroll
        for (int t = 0; t < 8; t++)
#pragma unroll
            for (int r = 0; r < 4; r++) {
                float x = acc[t][r] + hres[t][r];
                acc[t][r] = x;
                sum_[r] += x;
                sq_[r]  += x * x;
            }
#pragma unroll
        for (int m = 1; m < 16; m <<= 1)
#pragma unroll
            for (int r = 0; r < 4; r++) {
                sum_[r] += __shfl_xor(sum_[r], m);
                sq_[r]  += __shfl_xor(sq_[r], m);
            }
        float mean[4], rstd[4];
#pragma unroll
        for (int r = 0; r < 4; r++) {
            mean[r] = sum_[r] * (1.f / 128.f);
            float var = sq_[r] * (1.f / 128.f) - mean[r] * mean[r];
            rstd[r] = rsqrtf(fmaxf(var, 0.f) + 1e-5f);
        }
        float lgv[8], lbv[8];
#pragma unroll
        for (int t = 0; t < 8; t++) {
            lgv[t] = sLg[t * 16 + l15];
            lbv[t] = sLb[t * 16 + l15];
        }
        __bf16* hsp = hs + ((hh * 128 + b) * 128 + srow) * 128;
#pragma unroll
        for (int t = 0; t < 8; t++)
#pragma unroll
            for (int r = 0; r < 4; r++) {
                float y = (acc[t][r] - mean[r]) * rstd[r] * lgv[t] + lbv[t];
                hsp[r * 128 + t * 16 + l15] = (__bf16)(y * mw);
            }
    }
}

// ---------------------------------------------------------------------------
// 4) merge heads + prep next layer. Last layer writes f32 out = h[:,127,:].
// ---------------------------------------------------------------------------
__global__ void __launch_bounds__(128)
merge_kernel(const __bf16* __restrict__ hs, const float* __restrict__ mbp, int l,
             float* __restrict__ hf, __bf16* __restrict__ hb, float* __restrict__ invn,
             float* __restrict__ out, int last)
{
    __shared__ float sred[2];
    const int b = blockIdx.x & 127, s = blockIdx.x >> 7, d = threadIdx.x;

    float acc = mbp[l];
#pragma unroll
    for (int h = 0; h < 8; h++)
        acc += (float)hs[((h * 128 + b) * 128 + s) * 128 + d];

    float ss = block_sum_128(acc * acc, sred);

    const int o = (b * 128 + s) * 128 + d;
    hf[o] = acc;
    hb[o] = (__bf16)acc;
    if (d == 0) invn[b * 128 + s] = rsqrtf(ss);
    if (last && s == 127) out[b * 128 + d] = acc;   // f32 output
}

// ---------------------------------------------------------------------------
extern "C" void kernel_launch(void* const* d_in, const int* in_sizes, int n_in,
                              void* d_out, int out_size, void* d_ws, size_t ws_size,
                              hipStream_t stream)
{
    (void)in_sizes; (void)n_in; (void)out_size; (void)ws_size;

    const float* x   = (const float*)d_in[0];
    const float* ew  = (const float*)d_in[1];
    const float* eb  = (const float*)d_in[2];
    const float* ct  = (const float*)d_in[3];
    const float* g0  = (const float*)d_in[4];
    const float* b0  = (const float*)d_in[5];
    const float* vw  = (const float*)d_in[6];
    const float* vb  = (const float*)d_in[7];
    const float* lng = (const float*)d_in[8];
    const float* lnb = (const float*)d_in[9];
    const float* phi = (const float*)d_in[10];
    const float* mw  = (const float*)d_in[11];
    const float* mb  = (const float*)d_in[12];
    float* out = (float*)d_out;

    char* ws = (char*)d_ws;
    __bf16* wt   = (__bf16*)(ws);                 // 48*128*128*2   = 1,572,864
    float*  hf   = (float*)(ws + 1572864);        // 128*128*128*4  = 8,388,608
    __bf16* hb   = (__bf16*)(ws + 9961472);       // 128*128*128*2  = 4,194,304
    float*  invn = (float*)(ws + 14155776);       // 128*128*4      = 65,536
    __bf16* hs   = (__bf16*)(ws + 14221312);      // 8*128*128*128*2= 33,554,432
    __bf16* cvw  = (__bf16*)(ws + 47775744);      // 786432*2       = 1,572,864
                                                  // total ~49.3 MB

    vw_bf16_kernel<<<768, 256, 0, stream>>>(vw, cvw);
    build_w_kernel<<<768, 64, 0, stream>>>(phi, wt);
    embed_kernel<<<16384, 128, 0, stream>>>(x, ew, eb, ct, g0, b0, hf, hb, invn);
    for (int l = 0; l < 6; l++) {
        attn_kernel<<<1024, 512, 0, stream>>>(l, hf, hb, invn, wt, cvw, vb,
                                              lng, lnb, mw, hs);
        merge_kernel<<<16384, 128, 0, stream>>>(hs, mb, l, hf, hb, invn, out,
                                                (l == 5) ? 1 : 0);
    }
}

// Round 4
// 470.518 us; speedup vs baseline: 1.1567x; 1.1567x over previous
//
#include <hip/hip_runtime.h>
#include <hip/hip_bf16.h>

// ---------------------------------------------------------------------------
// Quantum ViT: B=128, T=127, D_IN=48, DK=S=128, H=8, L=6, P=8128
// Inputs: all float32 (per reference). Output: float32 [B, DK].
// Internals: bf16 MFMA (16x16x32) for the 4 matmuls per (layer,head);
// f32 residual path; harness compares in bf16 space (2%).
//
// Pipeline:
//   0) vw_bf16 : Vw f32 -> bf16 canon (B-operand staging)
//   0b) sincos : 48*254*64 (cos,sin) table, layer-major (t=253 pad = identity)
//   1) build_w : 48 orthogonal 128x128 Givens-pyramid matrices -> Wt=W^T bf16
//                (253 layers; table-fed, software-pipelined float2 loads)
//   2) embed   : x@Ew^T + class token, LN0 -> h_f32, h_bf16, inv_n
//   3) per layer: attn (per (head,batch) WG, fused 4-matmul attention)
//                 merge (sum heads + next-layer prep; last writes d_out f32)
// ---------------------------------------------------------------------------

typedef __bf16 bf16x8 __attribute__((ext_vector_type(8)));
typedef float  f32x4  __attribute__((ext_vector_type(4)));
typedef unsigned int u32;

#define LDH 136  // padded LDS row stride in bf16 elems

// ---------------------------------------------------------------------------
// 0) Vw f32 -> bf16
// ---------------------------------------------------------------------------
__global__ void __launch_bounds__(256)
vw_bf16_kernel(const float* __restrict__ vw, __bf16* __restrict__ cvw)
{
    int i = (blockIdx.x * 256 + threadIdx.x) * 4;   // 786432 elems / 4
#pragma unroll
    for (int j = 0; j < 4; j++) cvw[i + j] = (__bf16)vw[i + j];
}

// ---------------------------------------------------------------------------
// 0b) sincos table, layer-major: csn[(mat*254 + t)*64 + j] = (cos,sin) of the
//     theta used by pair i=2j+(t&1) at layer t (identity if inactive/pad).
//     Massively parallel -> sincos off build_w's critical path.
// ---------------------------------------------------------------------------
__global__ void __launch_bounds__(64)
sincos_kernel(const float* __restrict__ phi, float2* __restrict__ csn)
{
    const int mat = blockIdx.x / 254;
    const int t   = blockIdx.x % 254;
    const int j   = threadIdx.x;

    float th = 0.f;
    if (t < 253) {
        const int p = t & 1, i = 2 * j + p;
        const int lim = min(t, 252 - t);
        if (i <= lim) {
            const int k = (t + i) >> 1;
            th = phi[mat * 8128 + ((k * (k + 1)) >> 1) + (k - i)];
        }
    }
    float sn, cs;
    __sincosf(th, &sn, &cs);
    csn[(mat * 254 + t) * 64 + j] = make_float2(cs, sn);
}

// ---------------------------------------------------------------------------
// 1) W build: pyramid re-scheduled into 253 parallel layers via time(k,i)=2k-i
//    (program order preserved for every wire-sharing pair; within a layer
//    pairs are disjoint, same parity). Lane lam holds components (2lam,2lam+1)
//    of 8 columns. Even layer: in-lane rotate; odd: one shfl each way.
//    Table-fed (cos,sin); loads pipelined 2 layers deep.
//    Output: Wt[mat][c][d] = W[d][c]  (B-operand layout for T1 = h @ W).
// ---------------------------------------------------------------------------
__global__ void __launch_bounds__(64)
build_w_kernel(const float2* __restrict__ csn, __bf16* __restrict__ wt)
{
    const int mat = blockIdx.x >> 4;
    const int grp = blockIdx.x & 15;
    const int c0  = grp * 8;
    const int lam = threadIdx.x;

    const float2* base = csn + (mat * 254) * 64 + lam;

    float vlo[8], vhi[8];
#pragma unroll
    for (int j = 0; j < 8; j++) {
        vlo[j] = (2 * lam     == c0 + j) ? 1.f : 0.f;
        vhi[j] = (2 * lam + 1 == c0 + j) ? 1.f : 0.f;
    }

    float2 a  = base[0];      // layer t   (even)
    float2 bq = base[64];     // layer t+1 (odd)

    for (int t = 0; t < 252; t += 2) {
        // prefetch layers t+2, t+3 (pad row 253 = identity)
        float2 c2 = base[(t + 2) * 64];
        float2 d2 = base[(t + 3) * 64];

        {   // even layer: pairs (2lam, 2lam+1) in-lane
            const float cs = a.x, sn = a.y;
#pragma unroll
            for (int j = 0; j < 8; j++) {
                float lo = vlo[j], hi = vhi[j];
                vlo[j] = cs * lo - sn * hi;
                vhi[j] = sn * lo + cs * hi;
            }
        }
        {   // odd layer: pairs (2lam+1, 2lam+2) across lanes
            const float cs = bq.x, sn = bq.y;
#pragma unroll
            for (int j = 0; j < 8; j++) {
                float y  = __shfl_down(vlo[j], 1);   // W[2lam+2][c]
                float x  = vhi[j];                   // W[2lam+1][c]
                float xn = cs * x - sn * y;
                float yn = sn * x + cs * y;
                vhi[j] = xn;
                float z = __shfl_up(yn, 1);          // new W[2lam][c]
                if (lam > 0) vlo[j] = z;
            }
        }
        a = c2; bq = d2;
    }
    {   // final even layer t=252
        const float cs = a.x, sn = a.y;
#pragma unroll
        for (int j = 0; j < 8; j++) {
            float lo = vlo[j], hi = vhi[j];
            vlo[j] = cs * lo - sn * hi;
            vhi[j] = sn * lo + cs * hi;
        }
    }

    u32* wtu = (u32*)wt;
#pragma unroll
    for (int j = 0; j < 8; j++) {
        __bf16 va = (__bf16)vlo[j];
        __bf16 vb = (__bf16)vhi[j];
        u32 pk = (u32)__builtin_bit_cast(unsigned short, va)
               | ((u32)__builtin_bit_cast(unsigned short, vb) << 16);
        wtu[mat * 8192 + (c0 + j) * 64 + lam] = pk;   // Wt[mat][c0+j][2lam..2lam+1]
    }
}

// ---------------------------------------------------------------------------
static __device__ __forceinline__ float block_sum_128(float v, float* sred)
{
#pragma unroll
    for (int m = 32; m; m >>= 1) v += __shfl_xor(v, m);
    __syncthreads();
    if ((threadIdx.x & 63) == 0) sred[threadIdx.x >> 6] = v;
    __syncthreads();
    return sred[0] + sred[1];
}

// ---------------------------------------------------------------------------
// 2) embed: tok = x @ Ew^T + eb (class token at s=0), LN0 -> h_f32/h_bf16/inv_n
//    grid = s*128 + b, 128 threads (d)
// ---------------------------------------------------------------------------
__global__ void __launch_bounds__(128)
embed_kernel(const float* __restrict__ x,  const float* __restrict__ ew,
             const float* __restrict__ eb, const float* __restrict__ ct,
             const float* __restrict__ g0, const float* __restrict__ b0,
             float* __restrict__ hf, __bf16* __restrict__ hb, float* __restrict__ invn)
{
    __shared__ float sx[48];
    __shared__ float sred[2];
    const int b = blockIdx.x & 127, s = blockIdx.x >> 7, d = threadIdx.x;

    float val;
    if (s == 0) {
        val = ct[d];
    } else {
        if (d < 48) sx[d] = x[(b * 127 + (s - 1)) * 48 + d];
        __syncthreads();
        float aa = 0.f;
#pragma unroll
        for (int f = 0; f < 48; f++) aa = fmaf(sx[f], ew[d * 48 + f], aa);
        val = aa + eb[d];
    }
    float mean = block_sum_128(val, sred) * (1.f / 128.f);
    float xc   = val - mean;
    float var  = block_sum_128(xc * xc, sred) * (1.f / 128.f);
    float y    = xc * rsqrtf(var + 1e-5f) * g0[d] + b0[d];
    float ss   = block_sum_128(y * y, sred);

    const int o = (b * 128 + s) * 128 + d;
    hf[o] = y;
    hb[o] = (__bf16)y;
    if (d == 0) invn[b * 128 + s] = rsqrtf(ss);
}

// ---------------------------------------------------------------------------
// 3) fused attention head: one WG per (head, batch). 512 thr = 8 waves,
//    wave w owns rows 16w..16w+15 of every 128x128 matmul.
//    A: T1 = h @ W -> sT   | B: G = T1 @ h^T, softmax -> Pm in sT
//    C: V = h @ Vw^T       | D: O = Pm @ V, +h, LN, *mw -> hs
//    scores = G^2 * inv_ns * inv_nt * scale   (== M^2 * n_s n_t * scale)
// ---------------------------------------------------------------------------
__global__ void __launch_bounds__(512, 2)
attn_kernel(int l,
            const float*  __restrict__ hf,  const __bf16* __restrict__ hb,
            const float*  __restrict__ invn, const __bf16* __restrict__ wt,
            const __bf16* __restrict__ vw,  const float* __restrict__ vb,
            const float* __restrict__ lng,  const float* __restrict__ lnb,
            const float* __restrict__ mwp,  __bf16* __restrict__ hs)
{
    __shared__ __align__(16) __bf16 sH[128 * LDH];
    __shared__ __align__(16) __bf16 sB[128 * LDH];
    __shared__ __align__(16) __bf16 sT[128 * LDH];
    __shared__ float sInv[128];
    __shared__ float sVb[128];
    __shared__ float sLg[128];
    __shared__ float sLb[128];

    const int tid  = threadIdx.x;
    const int lane = tid & 63, wave = tid >> 6;
    const int l15  = lane & 15, quad = lane >> 4;
    const int b    = blockIdx.x & 127;
    const int hh   = blockIdx.x >> 7;
    const int lh   = l * 8 + hh;

    const __bf16* hbp = hb + b * 16384;
    const __bf16* wtp = wt + lh * 16384;
    const __bf16* vwp = vw + lh * 16384;

    bf16x8 vwr[4];
#pragma unroll
    for (int c = 0; c < 4; c++) {
        int ch  = tid + c * 512;
        int row = ch >> 4, cc = ch & 15;
        bf16x8 hv = *(const bf16x8*)(hbp + ch * 8);
        bf16x8 wv = *(const bf16x8*)(wtp + ch * 8);
        vwr[c]    = *(const bf16x8*)(vwp + ch * 8);
        *(bf16x8*)(&sH[row * LDH + cc * 8]) = hv;
        *(bf16x8*)(&sB[row * LDH + cc * 8]) = wv;
    }
    if (tid < 128) {
        sInv[tid] = invn[b * 128 + tid];
        sVb[tid]  = vb[lh * 128 + tid];
        sLg[tid]  = lng[lh * 128 + tid];
        sLb[tid]  = lnb[lh * 128 + tid];
    }
    __syncthreads();  // B1

    const int rowA = wave * 16 + l15;       // A-frag: m = lane&15
    const int kq   = quad * 8;              // A/B-frag: k = quad*8 + j
    const int srow = wave * 16 + quad * 4;  // C/D: row = quad*4 + reg
    const f32x4 vzero = {0.f, 0.f, 0.f, 0.f};

    f32x4 acc[8];

    // ================= Phase A: T1 = h @ W =================
#pragma unroll
    for (int t = 0; t < 8; t++) acc[t] = vzero;
#pragma unroll
    for (int k0 = 0; k0 < 128; k0 += 32) {
        bf16x8 af = *(const bf16x8*)(&sH[rowA * LDH + k0 + kq]);
#pragma unroll
        for (int t = 0; t < 8; t++) {
            bf16x8 bfr = *(const bf16x8*)(&sB[(t * 16 + l15) * LDH + k0 + kq]);
            acc[t] = __builtin_amdgcn_mfma_f32_16x16x32_bf16(af, bfr, acc[t], 0, 0, 0);
        }
    }
#pragma unroll
    for (int t = 0; t < 8; t++)
#pragma unroll
        for (int r = 0; r < 4; r++)
            sT[(srow + r) * LDH + t * 16 + l15] = (__bf16)acc[t][r];

    __syncthreads();  // B2: all done reading sB(Wt)

#pragma unroll
    for (int c = 0; c < 4; c++) {
        int ch = tid + c * 512; int row = ch >> 4, cc = ch & 15;
        *(bf16x8*)(&sB[row * LDH + cc * 8]) = vwr[c];
    }

    // ================= Phase B: G = T1 @ h^T =================
#pragma unroll
    for (int t = 0; t < 8; t++) acc[t] = vzero;
#pragma unroll
    for (int k0 = 0; k0 < 128; k0 += 32) {
        bf16x8 af = *(const bf16x8*)(&sT[rowA * LDH + k0 + kq]);
#pragma unroll
        for (int t = 0; t < 8; t++) {
            bf16x8 bfr = *(const bf16x8*)(&sH[(t * 16 + l15) * LDH + k0 + kq]);
            acc[t] = __builtin_amdgcn_mfma_f32_16x16x32_bf16(af, bfr, acc[t], 0, 0, 0);
        }
    }

    // ---- softmax over cols:  A = G^2 * inv_ns * inv_nt * scale ----
    {
        const float scale = 0.08838834764831843f;  // 1/sqrt(128)
        float invs[4], invt[8];
#pragma unroll
        for (int r = 0; r < 4; r++) invs[r] = sInv[srow + r];
#pragma unroll
        for (int t = 0; t < 8; t++) invt[t] = sInv[t * 16 + l15];

        float mx[4] = {-3e38f, -3e38f, -3e38f, -3e38f};
#pragma unroll
        for (int t = 0; t < 8; t++)
#pragma unroll
            for (int r = 0; r < 4; r++) {
                float g = acc[t][r];
                float v = g * g * invs[r] * invt[t] * scale;
                acc[t][r] = v;
                mx[r] = fmaxf(mx[r], v);
            }
#pragma unroll
        for (int m = 1; m < 16; m <<= 1)
#pragma unroll
            for (int r = 0; r < 4; r++) mx[r] = fmaxf(mx[r], __shfl_xor(mx[r], m));

        float sm[4] = {0.f, 0.f, 0.f, 0.f};
#pragma unroll
        for (int t = 0; t < 8; t++)
#pragma unroll
            for (int r = 0; r < 4; r++) {
                float e = __expf(acc[t][r] - mx[r]);
                acc[t][r] = e;
                sm[r] += e;
            }
#pragma unroll
        for (int m = 1; m < 16; m <<= 1)
#pragma unroll
            for (int r = 0; r < 4; r++) sm[r] += __shfl_xor(sm[r], m);
#pragma unroll
        for (int r = 0; r < 4; r++) sm[r] = 1.0f / sm[r];
#pragma unroll
        for (int t = 0; t < 8; t++)
#pragma unroll
            for (int r = 0; r < 4; r++)
                sT[(srow + r) * LDH + t * 16 + l15] = (__bf16)(acc[t][r] * sm[r]);
    }

    float hres[8][4];
    {
        const float* hfp = hf + (b * 128 + srow) * 128;
#pragma unroll
        for (int t = 0; t < 8; t++)
#pragma unroll
            for (int r = 0; r < 4; r++)
                hres[t][r] = hfp[r * 128 + t * 16 + l15];
    }

    __syncthreads();  // B3: Vw->sB visible

    // ================= Phase C: V = h @ Vw^T =================
#pragma unroll
    for (int t = 0; t < 8; t++) acc[t] = vzero;
#pragma unroll
    for (int k0 = 0; k0 < 128; k0 += 32) {
        bf16x8 af = *(const bf16x8*)(&sH[rowA * LDH + k0 + kq]);
#pragma unroll
        for (int t = 0; t < 8; t++) {
            bf16x8 bfr = *(const bf16x8*)(&sB[(t * 16 + l15) * LDH + k0 + kq]);
            acc[t] = __builtin_amdgcn_mfma_f32_16x16x32_bf16(af, bfr, acc[t], 0, 0, 0);
        }
    }
    __syncthreads();  // B4: all done reading sH

    {   // V^T into sH: sH[e][token]
        float vbv[8];
#pragma unroll
        for (int t = 0; t < 8; t++) vbv[t] = sVb[t * 16 + l15];
#pragma unroll
        for (int t = 0; t < 8; t++)
#pragma unroll
            for (int r = 0; r < 4; r++)
                sH[(t * 16 + l15) * LDH + srow + r] = (__bf16)(acc[t][r] + vbv[t]);
    }
    __syncthreads();  // B5

    // ================= Phase D: O = Pm @ V =================
#pragma unroll
    for (int t = 0; t < 8; t++) acc[t] = vzero;
#pragma unroll
    for (int k0 = 0; k0 < 128; k0 += 32) {
        bf16x8 af = *(const bf16x8*)(&sT[rowA * LDH + k0 + kq]);
#pragma unroll
        for (int t = 0; t < 8; t++) {
            bf16x8 bfr = *(const bf16x8*)(&sH[(t * 16 + l15) * LDH + k0 + kq]);
            acc[t] = __builtin_amdgcn_mfma_f32_16x16x32_bf16(af, bfr, acc[t], 0, 0, 0);
        }
    }

    {   // epilogue: +h, LN over d, *merger_w -> hs
        const float mw = mwp[lh];
        float sum_[4] = {0.f, 0.f, 0.f, 0.f};
        float sq_[4]  = {0.f, 0.f, 0.f, 0.f};
#pragma unroll
        for (int t = 0; t < 8; t++)
#pragma unroll
            for (int r = 0; r < 4; r++) {
                float x = acc[t][r] + hres[t][r];
                acc[t][r] = x;
                sum_[r] += x;
                sq_[r]  += x * x;
            }
#pragma unroll
        for (int m = 1; m < 16; m <<= 1)
#pragma unroll
            for (int r = 0; r < 4; r++) {
                sum_[r] += __shfl_xor(sum_[r], m);
                sq_[r]  += __shfl_xor(sq_[r], m);
            }
        float mean[4], rstd[4];
#pragma unroll
        for (int r = 0; r < 4; r++) {
            mean[r] = sum_[r] * (1.f / 128.f);
            float var = sq_[r] * (1.f / 128.f) - mean[r] * mean[r];
            rstd[r] = rsqrtf(fmaxf(var, 0.f) + 1e-5f);
        }
        float lgv[8], lbv[8];
#pragma unroll
        for (int t = 0; t < 8; t++) {
            lgv[t] = sLg[t * 16 + l15];
            lbv[t] = sLb[t * 16 + l15];
        }
        __bf16* hsp = hs + ((hh * 128 + b) * 128 + srow) * 128;
#pragma unroll
        for (int t = 0; t < 8; t++)
#pragma unroll
            for (int r = 0; r < 4; r++) {
                float y = (acc[t][r] - mean[r]) * rstd[r] * lgv[t] + lbv[t];
                hsp[r * 128 + t * 16 + l15] = (__bf16)(y * mw);
            }
    }
}

// ---------------------------------------------------------------------------
// 4) merge heads + prep next layer. Last layer writes f32 out = h[:,127,:].
// ---------------------------------------------------------------------------
__global__ void __launch_bounds__(128)
merge_kernel(const __bf16* __restrict__ hs, const float* __restrict__ mbp, int l,
             float* __restrict__ hf, __bf16* __restrict__ hb, float* __restrict__ invn,
             float* __restrict__ out, int last)
{
    __shared__ float sred[2];
    const int b = blockIdx.x & 127, s = blockIdx.x >> 7, d = threadIdx.x;

    float acc = mbp[l];
#pragma unroll
    for (int h = 0; h < 8; h++)
        acc += (float)hs[((h * 128 + b) * 128 + s) * 128 + d];

    float ss = block_sum_128(acc * acc, sred);

    const int o = (b * 128 + s) * 128 + d;
    hf[o] = acc;
    hb[o] = (__bf16)acc;
    if (d == 0) invn[b * 128 + s] = rsqrtf(ss);
    if (last && s == 127) out[b * 128 + d] = acc;   // f32 output
}

// ---------------------------------------------------------------------------
extern "C" void kernel_launch(void* const* d_in, const int* in_sizes, int n_in,
                              void* d_out, int out_size, void* d_ws, size_t ws_size,
                              hipStream_t stream)
{
    (void)in_sizes; (void)n_in; (void)out_size; (void)ws_size;

    const float* x   = (const float*)d_in[0];
    const float* ew  = (const float*)d_in[1];
    const float* eb  = (const float*)d_in[2];
    const float* ct  = (const float*)d_in[3];
    const float* g0  = (const float*)d_in[4];
    const float* b0  = (const float*)d_in[5];
    const float* vw  = (const float*)d_in[6];
    const float* vb  = (const float*)d_in[7];
    const float* lng = (const float*)d_in[8];
    const float* lnb = (const float*)d_in[9];
    const float* phi = (const float*)d_in[10];
    const float* mw  = (const float*)d_in[11];
    const float* mb  = (const float*)d_in[12];
    float* out = (float*)d_out;

    char* ws = (char*)d_ws;
    __bf16* wt   = (__bf16*)(ws);                 // 48*128*128*2   = 1,572,864
    float*  hf   = (float*)(ws + 1572864);        // 128*128*128*4  = 8,388,608
    __bf16* hb   = (__bf16*)(ws + 9961472);       // 128*128*128*2  = 4,194,304
    float*  invn = (float*)(ws + 14155776);       // 128*128*4      = 65,536
    __bf16* hs   = (__bf16*)(ws + 14221312);      // 8*128*128*128*2= 33,554,432
    __bf16* cvw  = (__bf16*)(ws + 47775744);      // 786432*2       = 1,572,864
    float2* csn  = (float2*)(ws + 49348608);      // 48*254*64*8    = 6,242,304
                                                  // total ~55.6 MB

    vw_bf16_kernel<<<768, 256, 0, stream>>>(vw, cvw);
    sincos_kernel<<<48 * 254, 64, 0, stream>>>(phi, csn);
    build_w_kernel<<<768, 64, 0, stream>>>(csn, wt);
    embed_kernel<<<16384, 128, 0, stream>>>(x, ew, eb, ct, g0, b0, hf, hb, invn);
    for (int l = 0; l < 6; l++) {
        attn_kernel<<<1024, 512, 0, stream>>>(l, hf, hb, invn, wt, cvw, vb,
                                              lng, lnb, mw, hs);
        merge_kernel<<<16384, 128, 0, stream>>>(hs, mb, l, hf, hb, invn, out,
                                                (l == 5) ? 1 : 0);
    }
}